// Round 12
// baseline (49.837 us; speedup 1.0000x reference)
//
#include <hip/hip_runtime.h>

#define NUM_INPUT   256
#define NUM_OUTPUT  64
#define N_INTERNAL  1023
#define STAGED_NODES 31          // tree levels 0..4 staged in LDS (31 KB)
#define THREADS 512              // 8 waves
#define NBLOCKS 1024             // 1024 * 8 waves * 4 groups * 4 elems = 131072

// Sum-reduce across each 16-lane row using DPP row_ror (VALU pipe, no DS ops).
__device__ __forceinline__ float group16_reduce_add(float acc) {
    int t;
    t = __builtin_amdgcn_update_dpp(0, __float_as_int(acc), 0x121, 0xf, 0xf, true);
    acc += __int_as_float(t);
    t = __builtin_amdgcn_update_dpp(0, __float_as_int(acc), 0x122, 0xf, 0xf, true);
    acc += __int_as_float(t);
    t = __builtin_amdgcn_update_dpp(0, __float_as_int(acc), 0x124, 0xf, 0xf, true);
    acc += __int_as_float(t);
    t = __builtin_amdgcn_update_dpp(0, __float_as_int(acc), 0x128, 0xf, 0xf, true);
    acc += __int_as_float(t);
    return acc;
}

// Product-reduce across each 16-lane row.
__device__ __forceinline__ float group16_reduce_mul(float v) {
    int t;
    t = __builtin_amdgcn_update_dpp(0, __float_as_int(v), 0x121, 0xf, 0xf, true);
    v *= __int_as_float(t);
    t = __builtin_amdgcn_update_dpp(0, __float_as_int(v), 0x122, 0xf, 0xf, true);
    v *= __int_as_float(t);
    t = __builtin_amdgcn_update_dpp(0, __float_as_int(v), 0x124, 0xf, 0xf, true);
    v *= __int_as_float(t);
    t = __builtin_amdgcn_update_dpp(0, __float_as_int(v), 0x128, 0xf, 0xf, true);
    v *= __int_as_float(t);
    return v;
}

// Issue element E's x row into the named register set; pin so it can't sink
// (proven on this base in R11: VGPR held, small win).
#define XISSUE(E, X0, X1, X2, X3)                                           \
    {                                                                       \
        const float4* xp_ = reinterpret_cast<const float4*>(                \
            x + (size_t)(gbase + 4 * (E)) * NUM_INPUT);                     \
        X0 = xp_[s]; X1 = xp_[16 + s]; X2 = xp_[32 + s]; X3 = xp_[48 + s];  \
        __builtin_amdgcn_sched_barrier(0);                                  \
    }

// Full LDS-level step (levels 0..4): ds_read row, dot, record -|z|, descend.
#define LSTEP(IDX, ZND, X0, X1, X2, X3)                                     \
    {                                                                       \
        float a_i = lds_a[IDX];                                             \
        float b_i = lds_b[IDX];                                             \
        const float4* wr_ = reinterpret_cast<const float4*>(                \
            lds_w + (size_t)(IDX) * NUM_INPUT);                             \
        float4 w0 = wr_[s], w1 = wr_[16 + s], w2 = wr_[32 + s], w3 = wr_[48 + s]; \
        float a0 = X0.x * w0.x, a1 = X1.x * w1.x;                           \
        float a2 = X2.x * w2.x, a3 = X3.x * w3.x;                           \
        a0 = fmaf(X0.y, w0.y, a0); a1 = fmaf(X1.y, w1.y, a1);               \
        a2 = fmaf(X2.y, w2.y, a2); a3 = fmaf(X3.y, w3.y, a3);               \
        a0 = fmaf(X0.z, w0.z, a0); a1 = fmaf(X1.z, w1.z, a1);               \
        a2 = fmaf(X2.z, w2.z, a2); a3 = fmaf(X3.z, w3.z, a3);               \
        a0 = fmaf(X0.w, w0.w, a0); a1 = fmaf(X1.w, w1.w, a1);               \
        a2 = fmaf(X2.w, w2.w, a2); a3 = fmaf(X3.w, w3.w, a3);               \
        float acc_ = group16_reduce_add((a0 + a1) + (a2 + a3));             \
        float z = a_i * (acc_ + b_i);                                       \
        ZND = __int_as_float(__float_as_int(z) | 0x80000000);               \
        IDX = 2 * (IDX) + 1 + ((z >= 0.0f) ? 1 : 0);                        \
    }

// Deep step split in two halves so an LSTEP can sit between issue & consume.
#define DISSUE(IDX)                                                         \
    {                                                                       \
        const float4* wr_ = reinterpret_cast<const float4*>(                \
            W + (size_t)(IDX) * NUM_INPUT);                                 \
        wd0 = wr_[s]; wd1 = wr_[16 + s]; wd2 = wr_[32 + s]; wd3 = wr_[48 + s]; \
    }
#define DCONSUME(IDX, ZND, X0, X1, X2, X3)                                  \
    {                                                                       \
        float a_i = lds_a[IDX];                                             \
        float b_i = lds_b[IDX];                                             \
        float a0 = X0.x * wd0.x, a1 = X1.x * wd1.x;                         \
        float a2 = X2.x * wd2.x, a3 = X3.x * wd3.x;                         \
        a0 = fmaf(X0.y, wd0.y, a0); a1 = fmaf(X1.y, wd1.y, a1);             \
        a2 = fmaf(X2.y, wd2.y, a2); a3 = fmaf(X3.y, wd3.y, a3);             \
        a0 = fmaf(X0.z, wd0.z, a0); a1 = fmaf(X1.z, wd1.z, a1);             \
        a2 = fmaf(X2.z, wd2.z, a2); a3 = fmaf(X3.z, wd3.z, a3);             \
        a0 = fmaf(X0.w, wd0.w, a0); a1 = fmaf(X1.w, wd1.w, a1);             \
        a2 = fmaf(X2.w, wd2.w, a2); a3 = fmaf(X3.w, wd3.w, a3);             \
        float acc_ = group16_reduce_add((a0 + a1) + (a2 + a3));             \
        float z = a_i * (acc_ + b_i);                                       \
        ZND = __int_as_float(__float_as_int(z) | 0x80000000);               \
        IDX = 2 * (IDX) + 1 + ((z >= 0.0f) ? 1 : 0);                        \
    }

// One steady-state tick: deep(eD) interleaved step-by-step with lds(eL).
#define DL_TICK(IDXD, IDXL, ZD5, ZD6, ZD7, ZD8, ZD9, ZL0, ZL1, ZL2, ZL3, ZL4, \
                XD0, XD1, XD2, XD3, XL0, XL1, XL2, XL3)                     \
    DISSUE(IDXD)                                                            \
    LSTEP(IDXL, ZL0, XL0, XL1, XL2, XL3)                                    \
    DCONSUME(IDXD, ZD5, XD0, XD1, XD2, XD3)                                 \
    DISSUE(IDXD)                                                            \
    LSTEP(IDXL, ZL1, XL0, XL1, XL2, XL3)                                    \
    DCONSUME(IDXD, ZD6, XD0, XD1, XD2, XD3)                                 \
    DISSUE(IDXD)                                                            \
    LSTEP(IDXL, ZL2, XL0, XL1, XL2, XL3)                                    \
    DCONSUME(IDXD, ZD7, XD0, XD1, XD2, XD3)                                 \
    DISSUE(IDXD)                                                            \
    LSTEP(IDXL, ZL3, XL0, XL1, XL2, XL3)                                    \
    DCONSUME(IDXD, ZD8, XD0, XD1, XD2, XD3)                                 \
    DISSUE(IDXD)                                                            \
    LSTEP(IDXL, ZL4, XL0, XL1, XL2, XL3)                                    \
    DCONSUME(IDXD, ZD9, XD0, XD1, XD2, XD3)

// Deferred-sigmoid epilogue + leaf multiply + store for element E.
#define EPI(E, IDX, Z0, Z1, Z2, Z3, Z4, Z5, Z6, Z7, Z8, Z9)                 \
    {                                                                       \
        float zsel = -1e30f;                                                \
        zsel = (s == 0) ? Z0 : zsel; zsel = (s == 1) ? Z1 : zsel;           \
        zsel = (s == 2) ? Z2 : zsel; zsel = (s == 3) ? Z3 : zsel;           \
        zsel = (s == 4) ? Z4 : zsel; zsel = (s == 5) ? Z5 : zsel;           \
        zsel = (s == 6) ? Z6 : zsel; zsel = (s == 7) ? Z7 : zsel;           \
        zsel = (s == 8) ? Z8 : zsel; zsel = (s == 9) ? Z9 : zsel;           \
        float f = 1.0f + __expf(zsel);                                      \
        float p = group16_reduce_mul(f);                                    \
        float mult = 1.0f / p;                                              \
        const int leaf = (IDX) - N_INTERNAL;                                \
        const float4 lv = reinterpret_cast<const float4*>(                  \
            leaves + (size_t)leaf * NUM_OUTPUT)[s];                         \
        float4 o;                                                           \
        o.x = mult * lv.x; o.y = mult * lv.y;                               \
        o.z = mult * lv.z; o.w = mult * lv.w;                               \
        reinterpret_cast<float4*>(                                          \
            out + (size_t)(gbase + 4 * (E)) * NUM_OUTPUT)[s] = o;           \
    }

__global__ __launch_bounds__(THREADS, 4) void ogtree_kernel(
    const float* __restrict__ x,
    const float* __restrict__ W,
    const float* __restrict__ b,
    const float* __restrict__ alpha,
    const float* __restrict__ leaves,
    float* __restrict__ out)
{
    __shared__ float lds_w[STAGED_NODES * NUM_INPUT];  // 31 KB
    __shared__ float lds_b[N_INTERNAL];                // 4 KB
    __shared__ float lds_a[N_INTERNAL];                // 4 KB

    const int tid  = threadIdx.x;
    const int lane = tid & 63;
    const int wid  = tid >> 6;
    const int g    = lane >> 4;   // element group within wave (0..3)
    const int s    = lane & 15;   // sub-lane within group
    const int gbase = blockIdx.x * (THREADS / 64) * 16 + wid * 16 + g;

    float4 xa0, xa1, xa2, xa3;    // rotating x register sets
    float4 xb0, xb1, xb2, xb3;
    float4 xc0, xc1, xc2, xc3;

    // ---- element 0's x issued BEFORE staging: latency hides under stage ----
    XISSUE(0, xa0, xa1, xa2, xa3)

    // ---- stage W levels 0..4 (rows 0..30) + all b/alpha ----
    {
        const float4* Wv = reinterpret_cast<const float4*>(W);
        float4* lw4 = reinterpret_cast<float4*>(lds_w);
        #pragma unroll
        for (int i = tid; i < STAGED_NODES * NUM_INPUT / 4; i += THREADS)
            lw4[i] = Wv[i];
        for (int i = tid; i < N_INTERNAL; i += THREADS) {
            lds_b[i] = b[i];
            lds_a[i] = alpha[i];
        }
    }
    __syncthreads();

    float ZA0, ZA1, ZA2, ZA3, ZA4, ZA5, ZA6, ZA7, ZA8, ZA9;
    float ZB0, ZB1, ZB2, ZB3, ZB4, ZB5, ZB6, ZB7, ZB8, ZB9;
    float4 wd0, wd1, wd2, wd3;    // in-flight deep W fragment
    int idxA, idxB;

    // T0: prefetch x(1)->B; lds-phase of element 0 [A]
    XISSUE(1, xb0, xb1, xb2, xb3)
    idxA = 0;
    LSTEP(idxA, ZA0, xa0, xa1, xa2, xa3)
    LSTEP(idxA, ZA1, xa0, xa1, xa2, xa3)
    LSTEP(idxA, ZA2, xa0, xa1, xa2, xa3)
    LSTEP(idxA, ZA3, xa0, xa1, xa2, xa3)
    LSTEP(idxA, ZA4, xa0, xa1, xa2, xa3)

    // T1: prefetch x(2)->C; deep(0)[A] || lds(1)[B]; epilogue(0)
    XISSUE(2, xc0, xc1, xc2, xc3)
    idxB = 0;
    DL_TICK(idxA, idxB, ZA5, ZA6, ZA7, ZA8, ZA9, ZB0, ZB1, ZB2, ZB3, ZB4,
            xa0, xa1, xa2, xa3, xb0, xb1, xb2, xb3)
    EPI(0, idxA, ZA0, ZA1, ZA2, ZA3, ZA4, ZA5, ZA6, ZA7, ZA8, ZA9)

    // T2: prefetch x(3)->A (A free after E(0)); deep(1)[B] || lds(2)[C]; E(1)
    XISSUE(3, xa0, xa1, xa2, xa3)
    idxA = 0;   // element 2 state
    DL_TICK(idxB, idxA, ZB5, ZB6, ZB7, ZB8, ZB9, ZA0, ZA1, ZA2, ZA3, ZA4,
            xb0, xb1, xb2, xb3, xc0, xc1, xc2, xc3)
    EPI(1, idxB, ZB0, ZB1, ZB2, ZB3, ZB4, ZB5, ZB6, ZB7, ZB8, ZB9)

    // T3: deep(2)[C] || lds(3)[A]; E(2)
    idxB = 0;   // element 3 state
    DL_TICK(idxA, idxB, ZA5, ZA6, ZA7, ZA8, ZA9, ZB0, ZB1, ZB2, ZB3, ZB4,
            xc0, xc1, xc2, xc3, xa0, xa1, xa2, xa3)
    EPI(2, idxA, ZA0, ZA1, ZA2, ZA3, ZA4, ZA5, ZA6, ZA7, ZA8, ZA9)

    // T4 (drain): deep(3)[A]; E(3)
    DISSUE(idxB)
    DCONSUME(idxB, ZB5, xa0, xa1, xa2, xa3)
    DISSUE(idxB)
    DCONSUME(idxB, ZB6, xa0, xa1, xa2, xa3)
    DISSUE(idxB)
    DCONSUME(idxB, ZB7, xa0, xa1, xa2, xa3)
    DISSUE(idxB)
    DCONSUME(idxB, ZB8, xa0, xa1, xa2, xa3)
    DISSUE(idxB)
    DCONSUME(idxB, ZB9, xa0, xa1, xa2, xa3)
    EPI(3, idxB, ZB0, ZB1, ZB2, ZB3, ZB4, ZB5, ZB6, ZB7, ZB8, ZB9)
}

extern "C" void kernel_launch(void* const* d_in, const int* in_sizes, int n_in,
                              void* d_out, int out_size, void* d_ws, size_t ws_size,
                              hipStream_t stream) {
    const float* x      = (const float*)d_in[0];
    const float* W      = (const float*)d_in[1];
    const float* b      = (const float*)d_in[2];
    const float* alpha  = (const float*)d_in[3];
    const float* leaves = (const float*)d_in[4];
    float* out = (float*)d_out;

    ogtree_kernel<<<NBLOCKS, THREADS, 0, stream>>>(x, W, b, alpha, leaves, out);
}

// Round 13
// 47.678 us; speedup vs baseline: 1.0453x; 1.0453x over previous
//
#include <hip/hip_runtime.h>

#define NUM_INPUT   256
#define NUM_OUTPUT  64
#define N_INTERNAL  1023
#define STAGED_NODES 63          // tree levels 0..5 staged in LDS (63 KB)
#define THREADS 1024             // 16 waves; 71KB LDS -> 2 blocks/CU
#define NBLOCKS 1024             // 1024 blk * 16 waves * 4 groups * 2 rounds = 131072
#define ROUNDS 2

// Sum-reduce across each 16-lane row using DPP row_ror (VALU pipe, no DS ops).
__device__ __forceinline__ float group16_reduce_add(float acc) {
    int t;
    t = __builtin_amdgcn_update_dpp(0, __float_as_int(acc), 0x121, 0xf, 0xf, true);
    acc += __int_as_float(t);
    t = __builtin_amdgcn_update_dpp(0, __float_as_int(acc), 0x122, 0xf, 0xf, true);
    acc += __int_as_float(t);
    t = __builtin_amdgcn_update_dpp(0, __float_as_int(acc), 0x124, 0xf, 0xf, true);
    acc += __int_as_float(t);
    t = __builtin_amdgcn_update_dpp(0, __float_as_int(acc), 0x128, 0xf, 0xf, true);
    acc += __int_as_float(t);
    return acc;
}

// Product-reduce across each 16-lane row.
__device__ __forceinline__ float group16_reduce_mul(float v) {
    int t;
    t = __builtin_amdgcn_update_dpp(0, __float_as_int(v), 0x121, 0xf, 0xf, true);
    v *= __int_as_float(t);
    t = __builtin_amdgcn_update_dpp(0, __float_as_int(v), 0x122, 0xf, 0xf, true);
    v *= __int_as_float(t);
    t = __builtin_amdgcn_update_dpp(0, __float_as_int(v), 0x124, 0xf, 0xf, true);
    v *= __int_as_float(t);
    t = __builtin_amdgcn_update_dpp(0, __float_as_int(v), 0x128, 0xf, 0xf, true);
    v *= __int_as_float(t);
    return v;
}

// Issue element E's x row into the named register set; pinned so the loads
// cannot sink to their uses (R11: proven held, -2.3us).
#define XISSUE(E, X0, X1, X2, X3)                                           \
    {                                                                       \
        const float4* xp_ = reinterpret_cast<const float4*>(                \
            x + (size_t)(gbase + 4 * (E)) * NUM_INPUT);                     \
        X0 = xp_[s]; X1 = xp_[16 + s]; X2 = xp_[32 + s]; X3 = xp_[48 + s];  \
        __builtin_amdgcn_sched_barrier(0);                                  \
    }

// One depth step; records -|z| (sigmoid deferred), decision via z>=0.
#define STEP_X(BASE, IDX, ZND, X0, X1, X2, X3)                              \
    {                                                                       \
        float a_i = lds_a[IDX];                                             \
        float b_i = lds_b[IDX];                                             \
        const float4* wr_ = reinterpret_cast<const float4*>(                \
            (BASE) + (size_t)(IDX) * NUM_INPUT);                            \
        float4 w0 = wr_[s], w1 = wr_[16 + s], w2 = wr_[32 + s], w3 = wr_[48 + s]; \
        float a0 = X0.x * w0.x, a1 = X1.x * w1.x;                           \
        float a2 = X2.x * w2.x, a3 = X3.x * w3.x;                           \
        a0 = fmaf(X0.y, w0.y, a0); a1 = fmaf(X1.y, w1.y, a1);               \
        a2 = fmaf(X2.y, w2.y, a2); a3 = fmaf(X3.y, w3.y, a3);               \
        a0 = fmaf(X0.z, w0.z, a0); a1 = fmaf(X1.z, w1.z, a1);               \
        a2 = fmaf(X2.z, w2.z, a2); a3 = fmaf(X3.z, w3.z, a3);               \
        a0 = fmaf(X0.w, w0.w, a0); a1 = fmaf(X1.w, w1.w, a1);               \
        a2 = fmaf(X2.w, w2.w, a2); a3 = fmaf(X3.w, w3.w, a3);               \
        float acc_ = group16_reduce_add((a0 + a1) + (a2 + a3));             \
        float z = a_i * (acc_ + b_i);                                       \
        ZND = __int_as_float(__float_as_int(z) | 0x80000000);               \
        IDX = 2 * (IDX) + 1 + ((z >= 0.0f) ? 1 : 0);                        \
    }

// Full traversal of element E with x set XC; optionally prefetch element
// E+1's x into XN during the deep phase.
#define ONE_ELEM(E, XC0, XC1, XC2, XC3, XN0, XN1, XN2, XN3, PF)             \
    {                                                                       \
        int idx = 0;                                                        \
        float zn0, zn1, zn2, zn3, zn4, zn5, zn6, zn7, zn8, zn9;             \
        /* depths 0..5 from LDS (DS pipe) */                                \
        STEP_X(lds_w, idx, zn0, XC0, XC1, XC2, XC3)                         \
        STEP_X(lds_w, idx, zn1, XC0, XC1, XC2, XC3)                         \
        STEP_X(lds_w, idx, zn2, XC0, XC1, XC2, XC3)                         \
        STEP_X(lds_w, idx, zn3, XC0, XC1, XC2, XC3)                         \
        STEP_X(lds_w, idx, zn4, XC0, XC1, XC2, XC3)                         \
        STEP_X(lds_w, idx, zn5, XC0, XC1, XC2, XC3)                         \
        if (PF) { XISSUE((E) + 1, XN0, XN1, XN2, XN3) }                     \
        /* depths 6..9 gathered from global (L2) — covers the prefetch */   \
        STEP_X(W, idx, zn6, XC0, XC1, XC2, XC3)                             \
        STEP_X(W, idx, zn7, XC0, XC1, XC2, XC3)                             \
        STEP_X(W, idx, zn8, XC0, XC1, XC2, XC3)                             \
        STEP_X(W, idx, zn9, XC0, XC1, XC2, XC3)                             \
        /* deferred sigmoid: mult = 1 / prod_d (1 + exp(-|z_d|)) */         \
        float zsel = -1e30f;                                                \
        zsel = (s == 0) ? zn0 : zsel; zsel = (s == 1) ? zn1 : zsel;         \
        zsel = (s == 2) ? zn2 : zsel; zsel = (s == 3) ? zn3 : zsel;         \
        zsel = (s == 4) ? zn4 : zsel; zsel = (s == 5) ? zn5 : zsel;         \
        zsel = (s == 6) ? zn6 : zsel; zsel = (s == 7) ? zn7 : zsel;         \
        zsel = (s == 8) ? zn8 : zsel; zsel = (s == 9) ? zn9 : zsel;         \
        float f = 1.0f + __expf(zsel);                                      \
        float p = group16_reduce_mul(f);                                    \
        float mult = 1.0f / p;                                              \
        const int leaf = idx - N_INTERNAL;                                  \
        const float4 lv = reinterpret_cast<const float4*>(                  \
            leaves + (size_t)leaf * NUM_OUTPUT)[s];                         \
        float4 o;                                                           \
        o.x = mult * lv.x; o.y = mult * lv.y;                               \
        o.z = mult * lv.z; o.w = mult * lv.w;                               \
        reinterpret_cast<float4*>(                                          \
            out + (size_t)(gbase + 4 * (E)) * NUM_OUTPUT)[s] = o;           \
    }

__global__ __launch_bounds__(THREADS) void ogtree_kernel(
    const float* __restrict__ x,
    const float* __restrict__ W,
    const float* __restrict__ b,
    const float* __restrict__ alpha,
    const float* __restrict__ leaves,
    float* __restrict__ out)
{
    __shared__ float lds_w[STAGED_NODES * NUM_INPUT];  // 63 KB
    __shared__ float lds_b[N_INTERNAL];                // 4 KB
    __shared__ float lds_a[N_INTERNAL];                // 4 KB

    const int tid  = threadIdx.x;
    const int lane = tid & 63;
    const int wid  = tid >> 6;
    const int g    = lane >> 4;   // element group within wave (0..3)
    const int s    = lane & 15;   // sub-lane within group
    // group's elements: gbase + 4*e (wave reads 4 consecutive elements
    // = contiguous 1KB per x-load round -> coalesced)
    const int gbase = blockIdx.x * (THREADS / 64) * (4 * ROUNDS)
                    + wid * (4 * ROUNDS) + g;

    float4 xa0, xa1, xa2, xa3;    // ping-pong x register sets
    float4 xb0, xb1, xb2, xb3;

    // ---- element 0's x issued BEFORE staging: latency hides under stage ----
    XISSUE(0, xa0, xa1, xa2, xa3)

    // ---- stage W levels 0..5 (rows 0..62) + all b/alpha ----
    {
        const float4* Wv = reinterpret_cast<const float4*>(W);
        float4* lw4 = reinterpret_cast<float4*>(lds_w);
        #pragma unroll
        for (int i = tid; i < STAGED_NODES * NUM_INPUT / 4; i += THREADS)
            lw4[i] = Wv[i];
        for (int i = tid; i < N_INTERNAL; i += THREADS) {
            lds_b[i] = b[i];
            lds_a[i] = alpha[i];
        }
    }
    __syncthreads();

    // e=0: compute from A, prefetch e=1 into B during deep phase
    ONE_ELEM(0, xa0, xa1, xa2, xa3, xb0, xb1, xb2, xb3, 1)
    // e=1: compute from B, no prefetch
    ONE_ELEM(1, xb0, xb1, xb2, xb3, xa0, xa1, xa2, xa3, 0)
}

extern "C" void kernel_launch(void* const* d_in, const int* in_sizes, int n_in,
                              void* d_out, int out_size, void* d_ws, size_t ws_size,
                              hipStream_t stream) {
    const float* x      = (const float*)d_in[0];
    const float* W      = (const float*)d_in[1];
    const float* b      = (const float*)d_in[2];
    const float* alpha  = (const float*)d_in[3];
    const float* leaves = (const float*)d_in[4];
    float* out = (float*)d_out;

    ogtree_kernel<<<NBLOCKS, THREADS, 0, stream>>>(x, W, b, alpha, leaves, out);
}